// Round 8
// baseline (711.623 us; speedup 1.0000x reference)
//
#include <hip/hip_runtime.h>
#include <math.h>

#define NNODES 50000
#define NEDGES 800000
#define D 128
#define NEG_SLOPE 0.2f
#define BN_EPS 1e-5f
#define SCAN_THREADS 1024
#define SCAN_CH 52                       // 13 x int4 per thread
#define COUNTS_PAD (SCAN_THREADS * SCAN_CH)   // 53248 >= 50000

// ============ CSR build (once per call; edge_index is layer-invariant) ======

__global__ __launch_bounds__(256) void k_hist(const int* __restrict__ dst,
        int* __restrict__ counts, int E) {
  int e = blockIdx.x * 256 + threadIdx.x;
  if (e < E) atomicAdd(&counts[dst[e]], 1);
}

// Single-workgroup fused scan, register-resident.
__global__ __launch_bounds__(1024) void k_scan_all(const int* __restrict__ counts,
        int* __restrict__ row_ptr, int* __restrict__ cursor, int n) {
  __shared__ int tsum[SCAN_THREADS];
  int t = threadIdx.x;
  int4 c[13];
  const int4* c4 = (const int4*)(counts + t * SCAN_CH);
  int s = 0;
#pragma unroll
  for (int k = 0; k < 13; ++k) {
    c[k] = c4[k];
    s += c[k].x + c[k].y + c[k].z + c[k].w;
  }
  tsum[t] = s;
  __syncthreads();
  for (int off = 1; off < SCAN_THREADS; off <<= 1) {
    int u = (t >= off) ? tsum[t - off] : 0;
    __syncthreads();
    tsum[t] += u;
    __syncthreads();
  }
  int run = tsum[t] - s;   // exclusive prefix of this thread's chunk
  int base = t * SCAN_CH;
#pragma unroll
  for (int k = 0; k < 13; ++k) {
    int i = base + k * 4;
    int4 v = c[k];
    if (i     < n) { cursor[i]     = run; run += v.x; row_ptr[i + 1] = run; }
    if (i + 1 < n) { cursor[i + 1] = run; run += v.y; row_ptr[i + 2] = run; }
    if (i + 2 < n) { cursor[i + 2] = run; run += v.z; row_ptr[i + 3] = run; }
    if (i + 3 < n) { cursor[i + 3] = run; run += v.w; row_ptr[i + 4] = run; }
  }
  if (t == 0) row_ptr[0] = 0;
}

__global__ __launch_bounds__(256) void k_scatter(const int* __restrict__ src,
        const int* __restrict__ dst, int* __restrict__ cursor,
        int* __restrict__ col_src, int E) {
  int e = blockIdx.x * 256 + threadIdx.x;
  if (e >= E) return;
  int slot = atomicAdd(&cursor[dst[e]], 1);
  col_src[slot] = src[e];
}

// ============ GEMM: LDS-tiled, register-blocked f32 ========================
__global__ __launch_bounds__(256) void k_gemm(const float* __restrict__ x,
        const float* __restrict__ Wl, const float* __restrict__ Wr,
        float* __restrict__ xl, float* __restrict__ xr, int n) {
  __shared__ float xs[64 * 128];
  __shared__ float wsd[128 * 64];
  const int t = threadIdx.x;
  const int row0 = blockIdx.x * 64;
  const int cb = blockIdx.y;
  const float* __restrict__ Wg = (cb < 2) ? Wl : Wr;
  float* __restrict__ outp = (cb < 2) ? xl : xr;
  const int cbase = (cb & 1) * 64;

  {
    int row = t >> 2, qr = t & 3;
    int grow = row0 + row;
    if (grow >= n) grow = n - 1;
    const float4* gp = (const float4*)(x + (size_t)grow * D + qr * 32);
#pragma unroll
    for (int m = 0; m < 8; ++m) {
      float4 v = gp[m];
      int byte = row * 512 + qr * 128 + m * 16;
      byte ^= (row & 7) << 4;
      *(float4*)((char*)xs + byte) = v;
    }
  }
  {
#pragma unroll
    for (int m = 0; m < 8; ++m) {
      int idx = m * 256 + t;
      int k = idx >> 4, c4 = idx & 15;
      float4 v = *(const float4*)(Wg + k * D + cbase + c4 * 4);
      *(float4*)((char*)wsd + k * 256 + c4 * 16) = v;
    }
  }
  __syncthreads();

  const int i = t & 15;
  const int j = t >> 4;
  float acc[4][4];
#pragma unroll
  for (int r = 0; r < 4; ++r)
#pragma unroll
    for (int c = 0; c < 4; ++c) acc[r][c] = 0.f;

  for (int kc = 0; kc < 32; ++kc) {
    float4 xv[4], wv[4];
#pragma unroll
    for (int rr = 0; rr < 4; ++rr) {
      int row = i + rr * 16;
      int byte = (row * 512 + kc * 16) ^ ((row & 7) << 4);
      xv[rr] = *(const float4*)((const char*)xs + byte);
    }
#pragma unroll
    for (int kk = 0; kk < 4; ++kk) {
      wv[kk] = *(const float4*)((const char*)wsd + (kc * 4 + kk) * 256 + j * 16);
    }
#pragma unroll
    for (int rr = 0; rr < 4; ++rr) {
      const float* xr_ = (const float*)&xv[rr];
#pragma unroll
      for (int kk = 0; kk < 4; ++kk) {
        const float* wr_ = (const float*)&wv[kk];
        float xk = xr_[kk];
        acc[rr][0] += xk * wr_[0];
        acc[rr][1] += xk * wr_[1];
        acc[rr][2] += xk * wr_[2];
        acc[rr][3] += xk * wr_[3];
      }
    }
  }

#pragma unroll
  for (int rr = 0; rr < 4; ++rr) {
    int grow = row0 + i + rr * 16;
    if (grow < n) {
      float4 v = make_float4(acc[rr][0], acc[rr][1], acc[rr][2], acc[rr][3]);
      *(float4*)(outp + (size_t)grow * D + cbase + j * 4) = v;
    }
  }
}

// ============ fused score + online-softmax + aggregate =====================
// 16 lanes per node (float8/lane), 4 nodes per wave. Gather stays 512B
// contiguous per row; score butterfly is 4 shfl_xor steps (within 16-lane
// group) and each wave instruction serves 4 edges (one per group).

__global__ __launch_bounds__(256) void k_agg(const float* __restrict__ xl,
        const float* __restrict__ xr, const int* __restrict__ col_src,
        const int* __restrict__ row_ptr, const float* __restrict__ att,
        float* __restrict__ out, int n) {
  int node = blockIdx.x * 16 + (threadIdx.x >> 4);
  if (node >= n) return;
  int lane = threadIdx.x & 15;
  const float4* xl4 = (const float4*)xl;
  int ro = lane * 2;                       // float4 index within row (row = 32 float4)
  float4 xr0 = ((const float4*)xr)[(size_t)node * 32 + ro];
  float4 xr1 = ((const float4*)xr)[(size_t)node * 32 + ro + 1];
  float4 at0 = ((const float4*)att)[ro];
  float4 at1 = ((const float4*)att)[ro + 1];

  int k0 = row_ptr[node], k1 = row_ptr[node + 1];
  float m = -1e30f, den = 0.f;
  float4 ac0 = make_float4(0.f, 0.f, 0.f, 0.f);
  float4 ac1 = make_float4(0.f, 0.f, 0.f, 0.f);

  for (int k = k0; k < k1; ++k) {
    int s = col_src[k];
    float4 v0 = xl4[(size_t)s * 32 + ro];
    float4 v1 = xl4[(size_t)s * 32 + ro + 1];
    // leaky_relu(v + xr) . att, partial over this lane's 8 channels
    float t0 = v0.x + xr0.x; t0 = t0 > 0.f ? t0 : NEG_SLOPE * t0;
    float t1 = v0.y + xr0.y; t1 = t1 > 0.f ? t1 : NEG_SLOPE * t1;
    float t2 = v0.z + xr0.z; t2 = t2 > 0.f ? t2 : NEG_SLOPE * t2;
    float t3 = v0.w + xr0.w; t3 = t3 > 0.f ? t3 : NEG_SLOPE * t3;
    float p = t0 * at0.x + t1 * at0.y + t2 * at0.z + t3 * at0.w;
    t0 = v1.x + xr1.x; t0 = t0 > 0.f ? t0 : NEG_SLOPE * t0;
    t1 = v1.y + xr1.y; t1 = t1 > 0.f ? t1 : NEG_SLOPE * t1;
    t2 = v1.z + xr1.z; t2 = t2 > 0.f ? t2 : NEG_SLOPE * t2;
    t3 = v1.w + xr1.w; t3 = t3 > 0.f ? t3 : NEG_SLOPE * t3;
    p += t0 * at1.x + t1 * at1.y + t2 * at1.z + t3 * at1.w;
    // 4-step butterfly within the 16-lane group
    p += __shfl_xor(p, 1);
    p += __shfl_xor(p, 2);
    p += __shfl_xor(p, 4);
    p += __shfl_xor(p, 8);
    // online softmax (branch uniform within the group)
    if (p > m) {
      float sc = __expf(m - p);
      den *= sc;
      ac0.x *= sc; ac0.y *= sc; ac0.z *= sc; ac0.w *= sc;
      ac1.x *= sc; ac1.y *= sc; ac1.z *= sc; ac1.w *= sc;
      m = p;
    }
    float a = __expf(p - m);
    den += a;
    ac0.x += a * v0.x; ac0.y += a * v0.y; ac0.z += a * v0.z; ac0.w += a * v0.w;
    ac1.x += a * v1.x; ac1.y += a * v1.y; ac1.z += a * v1.z; ac1.w += a * v1.w;
  }

  float inv = 1.f / (den + 1e-16f);
  float4* o4 = (float4*)out;
  o4[(size_t)node * 32 + ro]     = make_float4(ac0.x * inv, ac0.y * inv, ac0.z * inv, ac0.w * inv);
  o4[(size_t)node * 32 + ro + 1] = make_float4(ac1.x * inv, ac1.y * inv, ac1.z * inv, ac1.w * inv);
}

// ============ BatchNorm + GELU =============================================

__global__ __launch_bounds__(256) void k_bn_stats(const float* __restrict__ agg,
        float* __restrict__ sums, int n) {
  int c = threadIdx.x & 127;
  int half = threadIdx.x >> 7;
  float s = 0.f, s2 = 0.f;
  for (int r = blockIdx.x * 2 + half; r < n; r += gridDim.x * 2) {
    float v = agg[(size_t)r * D + c];
    s += v;
    s2 += v * v;
  }
  atomicAdd(&sums[c], s);
  atomicAdd(&sums[D + c], s2);
}

__global__ void k_bn_fin(const float* __restrict__ sums, const float* __restrict__ gamma,
        const float* __restrict__ beta, float* __restrict__ ss, float inv_n) {
  int c = threadIdx.x;
  float mu = sums[c] * inv_n;
  float var = sums[D + c] * inv_n - mu * mu;
  float rs = rsqrtf(var + BN_EPS);
  float sc = gamma[c] * rs;
  ss[c] = sc;
  ss[D + c] = beta[c] - mu * sc;
}

__global__ __launch_bounds__(256) void k_bn_apply(const float* __restrict__ agg,
        const float* __restrict__ ss, float* __restrict__ xo, int total4) {
  int i = blockIdx.x * 256 + threadIdx.x;
  if (i >= total4) return;
  float4 v = ((const float4*)agg)[i];
  int c4 = i & (D / 4 - 1);
  float4 sc = ((const float4*)ss)[c4];
  float4 sh = ((const float4*)ss)[D / 4 + c4];
  float y0 = sc.x * v.x + sh.x;
  float y1 = sc.y * v.y + sh.y;
  float y2 = sc.z * v.z + sh.z;
  float y3 = sc.w * v.w + sh.w;
  float4 g;
  g.x = 0.5f * y0 * (1.f + erff(y0 * 0.70710678118654752f));
  g.y = 0.5f * y1 * (1.f + erff(y1 * 0.70710678118654752f));
  g.z = 0.5f * y2 * (1.f + erff(y2 * 0.70710678118654752f));
  g.w = 0.5f * y3 * (1.f + erff(y3 * 0.70710678118654752f));
  ((float4*)xo)[i] = g;
}

// ===========================================================================

extern "C" void kernel_launch(void* const* d_in, const int* in_sizes, int n_in,
                              void* d_out, int out_size, void* d_ws, size_t ws_size,
                              hipStream_t stream) {
  const float* x0    = (const float*)d_in[0];
  const int*   ei    = (const int*)d_in[1];
  const float* Wl    = (const float*)d_in[2];
  const float* Wr    = (const float*)d_in[3];
  const float* att   = (const float*)d_in[4];
  // d_in[5] = bias: cancelled exactly by BatchNorm mean-subtraction; unused.
  const float* gamma = (const float*)d_in[6];
  const float* beta  = (const float*)d_in[7];
  float* out = (float*)d_out;

  float* ws = (float*)d_ws;
  float* xl      = ws;                          // 6,400,000
  float* xr      = ws + 6400000;                // 6,400,000
  int*   col_src = (int*)(ws + 12800000);       //   800,000
  int*   row_ptr = (int*)(ws + 13600000);       //    50,001
  int*   cursor  = (int*)(ws + 13650004);       //    50,000
  int*   counts  = (int*)(ws + 13700004);       // COUNTS_PAD (16B-aligned)
  float* sums    = ws + 13753252;               //       256
  float* ss      = ws + 13753508;               //       256

  const int* src = ei;
  const int* dst = ei + NEDGES;

  // ---- build CSR by destination (once; reused for all 3 layers) ----
  hipMemsetAsync(counts, 0, COUNTS_PAD * sizeof(int), stream);
  k_hist<<<(NEDGES + 255) / 256, 256, 0, stream>>>(dst, counts, NEDGES);
  k_scan_all<<<1, SCAN_THREADS, 0, stream>>>(counts, row_ptr, cursor, NNODES);
  k_scatter<<<(NEDGES + 255) / 256, 256, 0, stream>>>(src, dst, cursor, col_src, NEDGES);

  dim3 ggrid((NNODES + 63) / 64, 4);

  for (int l = 0; l < 3; ++l) {
    const float* xin = (l == 0) ? x0 : out;

    k_gemm<<<ggrid, 256, 0, stream>>>(xin, Wl + l * D * D, Wr + l * D * D,
                                      xl, xr, NNODES);
    hipMemsetAsync(sums, 0, 2 * D * sizeof(float), stream);

    // d_out is dead as an input after k_gemm -> safe to overwrite with agg.
    k_agg<<<(NNODES + 15) / 16, 256, 0, stream>>>(xl, xr, col_src, row_ptr,
                                                  att + l * D, out, NNODES);

    k_bn_stats<<<512, 256, 0, stream>>>(out, sums, NNODES);
    k_bn_fin<<<1, D, 0, stream>>>(sums, gamma + l * D, beta + l * D, ss, 1.0f / NNODES);
    k_bn_apply<<<(NNODES * (D / 4) + 255) / 256, 256, 0, stream>>>(out, ss, out, NNODES * (D / 4));
  }
}

// Round 9
// 677.249 us; speedup vs baseline: 1.0508x; 1.0508x over previous
//
#include <hip/hip_runtime.h>
#include <math.h>

#define NNODES 50000
#define NEDGES 800000
#define D 128
#define NEG_SLOPE 0.2f
#define BN_EPS 1e-5f
#define SCAN_THREADS 1024
#define SCAN_CH 52                       // 13 x int4 per thread
#define COUNTS_PAD (SCAN_THREADS * SCAN_CH)   // 53248 >= 50000

typedef __attribute__((ext_vector_type(8))) unsigned short ushort8_t;

// RNE float -> bf16 (no NaN handling needed for this data)
__device__ __forceinline__ unsigned short f2bf(float x) {
  unsigned u = __float_as_uint(x);
  u += 0x7fffu + ((u >> 16) & 1u);
  return (unsigned short)(u >> 16);
}
__device__ __forceinline__ float bf2f(unsigned short h) {
  return __uint_as_float((unsigned)h << 16);
}

// ============ CSR build (once per call; edge_index is layer-invariant) ======

__global__ __launch_bounds__(256) void k_hist(const int* __restrict__ dst,
        int* __restrict__ counts, int E) {
  int e = blockIdx.x * 256 + threadIdx.x;
  if (e < E) atomicAdd(&counts[dst[e]], 1);
}

// Single-workgroup fused scan, register-resident.
__global__ __launch_bounds__(1024) void k_scan_all(const int* __restrict__ counts,
        int* __restrict__ row_ptr, int* __restrict__ cursor, int n) {
  __shared__ int tsum[SCAN_THREADS];
  int t = threadIdx.x;
  int4 c[13];
  const int4* c4 = (const int4*)(counts + t * SCAN_CH);
  int s = 0;
#pragma unroll
  for (int k = 0; k < 13; ++k) {
    c[k] = c4[k];
    s += c[k].x + c[k].y + c[k].z + c[k].w;
  }
  tsum[t] = s;
  __syncthreads();
  for (int off = 1; off < SCAN_THREADS; off <<= 1) {
    int u = (t >= off) ? tsum[t - off] : 0;
    __syncthreads();
    tsum[t] += u;
    __syncthreads();
  }
  int run = tsum[t] - s;   // exclusive prefix of this thread's chunk
  int base = t * SCAN_CH;
#pragma unroll
  for (int k = 0; k < 13; ++k) {
    int i = base + k * 4;
    int4 v = c[k];
    if (i     < n) { cursor[i]     = run; run += v.x; row_ptr[i + 1] = run; }
    if (i + 1 < n) { cursor[i + 1] = run; run += v.y; row_ptr[i + 2] = run; }
    if (i + 2 < n) { cursor[i + 2] = run; run += v.z; row_ptr[i + 3] = run; }
    if (i + 3 < n) { cursor[i + 3] = run; run += v.w; row_ptr[i + 4] = run; }
  }
  if (t == 0) row_ptr[0] = 0;
}

__global__ __launch_bounds__(256) void k_scatter(const int* __restrict__ src,
        const int* __restrict__ dst, int* __restrict__ cursor,
        int* __restrict__ col_src, int E) {
  int e = blockIdx.x * 256 + threadIdx.x;
  if (e >= E) return;
  int slot = atomicAdd(&cursor[dst[e]], 1);
  col_src[slot] = src[e];
}

// ============ GEMM: LDS-tiled, register-blocked f32 ========================
// xl output (cb<2) is stored as bf16 (gather operand); xr stays f32.
__global__ __launch_bounds__(256) void k_gemm(const float* __restrict__ x,
        const float* __restrict__ Wl, const float* __restrict__ Wr,
        unsigned short* __restrict__ xlb, float* __restrict__ xr, int n) {
  __shared__ float xs[64 * 128];
  __shared__ float wsd[128 * 64];
  const int t = threadIdx.x;
  const int row0 = blockIdx.x * 64;
  const int cb = blockIdx.y;
  const float* __restrict__ Wg = (cb < 2) ? Wl : Wr;
  const int cbase = (cb & 1) * 64;

  {
    int row = t >> 2, qr = t & 3;
    int grow = row0 + row;
    if (grow >= n) grow = n - 1;
    const float4* gp = (const float4*)(x + (size_t)grow * D + qr * 32);
#pragma unroll
    for (int m = 0; m < 8; ++m) {
      float4 v = gp[m];
      int byte = row * 512 + qr * 128 + m * 16;
      byte ^= (row & 7) << 4;
      *(float4*)((char*)xs + byte) = v;
    }
  }
  {
#pragma unroll
    for (int m = 0; m < 8; ++m) {
      int idx = m * 256 + t;
      int k = idx >> 4, c4 = idx & 15;
      float4 v = *(const float4*)(Wg + k * D + cbase + c4 * 4);
      *(float4*)((char*)wsd + k * 256 + c4 * 16) = v;
    }
  }
  __syncthreads();

  const int i = t & 15;
  const int j = t >> 4;
  float acc[4][4];
#pragma unroll
  for (int r = 0; r < 4; ++r)
#pragma unroll
    for (int c = 0; c < 4; ++c) acc[r][c] = 0.f;

  for (int kc = 0; kc < 32; ++kc) {
    float4 xv[4], wv[4];
#pragma unroll
    for (int rr = 0; rr < 4; ++rr) {
      int row = i + rr * 16;
      int byte = (row * 512 + kc * 16) ^ ((row & 7) << 4);
      xv[rr] = *(const float4*)((const char*)xs + byte);
    }
#pragma unroll
    for (int kk = 0; kk < 4; ++kk) {
      wv[kk] = *(const float4*)((const char*)wsd + (kc * 4 + kk) * 256 + j * 16);
    }
#pragma unroll
    for (int rr = 0; rr < 4; ++rr) {
      const float* xr_ = (const float*)&xv[rr];
#pragma unroll
      for (int kk = 0; kk < 4; ++kk) {
        const float* wr_ = (const float*)&wv[kk];
        float xk = xr_[kk];
        acc[rr][0] += xk * wr_[0];
        acc[rr][1] += xk * wr_[1];
        acc[rr][2] += xk * wr_[2];
        acc[rr][3] += xk * wr_[3];
      }
    }
  }

  if (cb < 2) {
#pragma unroll
    for (int rr = 0; rr < 4; ++rr) {
      int grow = row0 + i + rr * 16;
      if (grow < n) {
        uint2 pk;
        pk.x = (unsigned)f2bf(acc[rr][0]) | ((unsigned)f2bf(acc[rr][1]) << 16);
        pk.y = (unsigned)f2bf(acc[rr][2]) | ((unsigned)f2bf(acc[rr][3]) << 16);
        *(uint2*)(xlb + (size_t)grow * D + cbase + j * 4) = pk;
      }
    }
  } else {
#pragma unroll
    for (int rr = 0; rr < 4; ++rr) {
      int grow = row0 + i + rr * 16;
      if (grow < n) {
        float4 v = make_float4(acc[rr][0], acc[rr][1], acc[rr][2], acc[rr][3]);
        *(float4*)(xr + (size_t)grow * D + cbase + j * 4) = v;
      }
    }
  }
}

// ============ fused score + online-softmax + aggregate =====================
// 16 lanes per node, 4 nodes per wave. xl gathered as bf16: one 16B
// ushort8 load per edge per lane (256B per row per 16-lane group).

__global__ __launch_bounds__(256) void k_agg(const unsigned short* __restrict__ xlb,
        const float* __restrict__ xr, const int* __restrict__ col_src,
        const int* __restrict__ row_ptr, const float* __restrict__ att,
        float* __restrict__ out, int n) {
  int node = blockIdx.x * 16 + (threadIdx.x >> 4);
  if (node >= n) return;
  int lane = threadIdx.x & 15;
  int ro = lane * 2;                       // float4 index within row
  float4 xr0 = ((const float4*)xr)[(size_t)node * 32 + ro];
  float4 xr1 = ((const float4*)xr)[(size_t)node * 32 + ro + 1];
  float4 at0 = ((const float4*)att)[ro];
  float4 at1 = ((const float4*)att)[ro + 1];

  int k0 = row_ptr[node], k1 = row_ptr[node + 1];
  float m = -1e30f, den = 0.f;
  float ac[8];
#pragma unroll
  for (int j = 0; j < 8; ++j) ac[j] = 0.f;

  for (int k = k0; k < k1; ++k) {
    int s = col_src[k];
    ushort8_t hv = ((const ushort8_t*)(xlb + (size_t)s * D))[lane];
    float v[8];
#pragma unroll
    for (int j = 0; j < 8; ++j) v[j] = bf2f(hv[j]);
    // leaky_relu(v + xr) . att over this lane's 8 channels
    float t0, p;
    t0 = v[0] + xr0.x; t0 = t0 > 0.f ? t0 : NEG_SLOPE * t0; p  = t0 * at0.x;
    t0 = v[1] + xr0.y; t0 = t0 > 0.f ? t0 : NEG_SLOPE * t0; p += t0 * at0.y;
    t0 = v[2] + xr0.z; t0 = t0 > 0.f ? t0 : NEG_SLOPE * t0; p += t0 * at0.z;
    t0 = v[3] + xr0.w; t0 = t0 > 0.f ? t0 : NEG_SLOPE * t0; p += t0 * at0.w;
    t0 = v[4] + xr1.x; t0 = t0 > 0.f ? t0 : NEG_SLOPE * t0; p += t0 * at1.x;
    t0 = v[5] + xr1.y; t0 = t0 > 0.f ? t0 : NEG_SLOPE * t0; p += t0 * at1.y;
    t0 = v[6] + xr1.z; t0 = t0 > 0.f ? t0 : NEG_SLOPE * t0; p += t0 * at1.z;
    t0 = v[7] + xr1.w; t0 = t0 > 0.f ? t0 : NEG_SLOPE * t0; p += t0 * at1.w;
    // 4-step butterfly within the 16-lane group
    p += __shfl_xor(p, 1);
    p += __shfl_xor(p, 2);
    p += __shfl_xor(p, 4);
    p += __shfl_xor(p, 8);
    // online softmax (branch uniform within the group)
    if (p > m) {
      float sc = __expf(m - p);
      den *= sc;
#pragma unroll
      for (int j = 0; j < 8; ++j) ac[j] *= sc;
      m = p;
    }
    float a = __expf(p - m);
    den += a;
#pragma unroll
    for (int j = 0; j < 8; ++j) ac[j] += a * v[j];
  }

  float inv = 1.f / (den + 1e-16f);
  float4* o4 = (float4*)out;
  o4[(size_t)node * 32 + ro]     = make_float4(ac[0] * inv, ac[1] * inv, ac[2] * inv, ac[3] * inv);
  o4[(size_t)node * 32 + ro + 1] = make_float4(ac[4] * inv, ac[5] * inv, ac[6] * inv, ac[7] * inv);
}

// ============ BatchNorm + GELU =============================================

__global__ __launch_bounds__(256) void k_bn_stats(const float* __restrict__ agg,
        float* __restrict__ sums, int n) {
  int c = threadIdx.x & 127;
  int half = threadIdx.x >> 7;
  float s = 0.f, s2 = 0.f;
  for (int r = blockIdx.x * 2 + half; r < n; r += gridDim.x * 2) {
    float v = agg[(size_t)r * D + c];
    s += v;
    s2 += v * v;
  }
  atomicAdd(&sums[c], s);
  atomicAdd(&sums[D + c], s2);
}

__global__ void k_bn_fin(const float* __restrict__ sums, const float* __restrict__ gamma,
        const float* __restrict__ beta, float* __restrict__ ss, float inv_n) {
  int c = threadIdx.x;
  float mu = sums[c] * inv_n;
  float var = sums[D + c] * inv_n - mu * mu;
  float rs = rsqrtf(var + BN_EPS);
  float sc = gamma[c] * rs;
  ss[c] = sc;
  ss[D + c] = beta[c] - mu * sc;
}

__global__ __launch_bounds__(256) void k_bn_apply(const float* __restrict__ agg,
        const float* __restrict__ ss, float* __restrict__ xo, int total4) {
  int i = blockIdx.x * 256 + threadIdx.x;
  if (i >= total4) return;
  float4 v = ((const float4*)agg)[i];
  int c4 = i & (D / 4 - 1);
  float4 sc = ((const float4*)ss)[c4];
  float4 sh = ((const float4*)ss)[D / 4 + c4];
  float y0 = sc.x * v.x + sh.x;
  float y1 = sc.y * v.y + sh.y;
  float y2 = sc.z * v.z + sh.z;
  float y3 = sc.w * v.w + sh.w;
  float4 g;
  g.x = 0.5f * y0 * (1.f + erff(y0 * 0.70710678118654752f));
  g.y = 0.5f * y1 * (1.f + erff(y1 * 0.70710678118654752f));
  g.z = 0.5f * y2 * (1.f + erff(y2 * 0.70710678118654752f));
  g.w = 0.5f * y3 * (1.f + erff(y3 * 0.70710678118654752f));
  ((float4*)xo)[i] = g;
}

// ===========================================================================

extern "C" void kernel_launch(void* const* d_in, const int* in_sizes, int n_in,
                              void* d_out, int out_size, void* d_ws, size_t ws_size,
                              hipStream_t stream) {
  const float* x0    = (const float*)d_in[0];
  const int*   ei    = (const int*)d_in[1];
  const float* Wl    = (const float*)d_in[2];
  const float* Wr    = (const float*)d_in[3];
  const float* att   = (const float*)d_in[4];
  // d_in[5] = bias: cancelled exactly by BatchNorm mean-subtraction; unused.
  const float* gamma = (const float*)d_in[6];
  const float* beta  = (const float*)d_in[7];
  float* out = (float*)d_out;

  float* ws = (float*)d_ws;
  unsigned short* xlb = (unsigned short*)ws;    // 6,400,000 ushorts (3.2M floats)
  float* xr      = ws + 3200000;                // 6,400,000
  int*   col_src = (int*)(ws + 9600000);        //   800,000
  int*   row_ptr = (int*)(ws + 10400000);       //    50,001
  int*   cursor  = (int*)(ws + 10450004);       //    50,000
  int*   counts  = (int*)(ws + 10500004);       // COUNTS_PAD (16B-aligned)
  float* sums    = ws + 10553252;               //       256
  float* ss      = ws + 10553508;               //       256

  const int* src = ei;
  const int* dst = ei + NEDGES;

  // ---- build CSR by destination (once; reused for all 3 layers) ----
  hipMemsetAsync(counts, 0, COUNTS_PAD * sizeof(int), stream);
  k_hist<<<(NEDGES + 255) / 256, 256, 0, stream>>>(dst, counts, NEDGES);
  k_scan_all<<<1, SCAN_THREADS, 0, stream>>>(counts, row_ptr, cursor, NNODES);
  k_scatter<<<(NEDGES + 255) / 256, 256, 0, stream>>>(src, dst, cursor, col_src, NEDGES);

  dim3 ggrid((NNODES + 63) / 64, 4);

  for (int l = 0; l < 3; ++l) {
    const float* xin = (l == 0) ? x0 : out;

    k_gemm<<<ggrid, 256, 0, stream>>>(xin, Wl + l * D * D, Wr + l * D * D,
                                      xlb, xr, NNODES);
    hipMemsetAsync(sums, 0, 2 * D * sizeof(float), stream);

    // d_out is dead as an input after k_gemm -> safe to overwrite with agg.
    k_agg<<<(NNODES + 15) / 16, 256, 0, stream>>>(xlb, xr, col_src, row_ptr,
                                                  att + l * D, out, NNODES);

    k_bn_stats<<<512, 256, 0, stream>>>(out, sums, NNODES);
    k_bn_fin<<<1, D, 0, stream>>>(sums, gamma + l * D, beta + l * D, ss, 1.0f / NNODES);
    k_bn_apply<<<(NNODES * (D / 4) + 255) / 256, 256, 0, stream>>>(out, ss, out, NNODES * (D / 4));
  }
}

// Round 10
// 586.624 us; speedup vs baseline: 1.2131x; 1.1545x over previous
//
#include <hip/hip_runtime.h>
#include <math.h>

#define NNODES 50000
#define NEDGES 800000
#define D 128
#define NEG_SLOPE 0.2f
#define BN_EPS 1e-5f
#define SCAN_THREADS 1024
#define SCAN_CH 52                       // 13 x int4 per thread
#define COUNTS_PAD (SCAN_THREADS * SCAN_CH)   // 53248 >= 50000

typedef __attribute__((ext_vector_type(8))) unsigned short ushort8_t;
typedef __attribute__((ext_vector_type(8))) short bf16x8;
typedef __attribute__((ext_vector_type(4))) float f32x4;

// RNE float -> bf16
__device__ __forceinline__ unsigned short f2bf(float x) {
  unsigned u = __float_as_uint(x);
  u += 0x7fffu + ((u >> 16) & 1u);
  return (unsigned short)(u >> 16);
}
__device__ __forceinline__ float bf2f(unsigned short h) {
  return __uint_as_float((unsigned)h << 16);
}

// ============ CSR build (once per call) ====================================

__global__ __launch_bounds__(256) void k_hist(const int* __restrict__ dst,
        int* __restrict__ counts, int E) {
  int e = blockIdx.x * 256 + threadIdx.x;
  if (e < E) atomicAdd(&counts[dst[e]], 1);
}

__global__ __launch_bounds__(1024) void k_scan_all(const int* __restrict__ counts,
        int* __restrict__ row_ptr, int* __restrict__ cursor, int n) {
  __shared__ int tsum[SCAN_THREADS];
  int t = threadIdx.x;
  int4 c[13];
  const int4* c4 = (const int4*)(counts + t * SCAN_CH);
  int s = 0;
#pragma unroll
  for (int k = 0; k < 13; ++k) {
    c[k] = c4[k];
    s += c[k].x + c[k].y + c[k].z + c[k].w;
  }
  tsum[t] = s;
  __syncthreads();
  for (int off = 1; off < SCAN_THREADS; off <<= 1) {
    int u = (t >= off) ? tsum[t - off] : 0;
    __syncthreads();
    tsum[t] += u;
    __syncthreads();
  }
  int run = tsum[t] - s;
  int base = t * SCAN_CH;
#pragma unroll
  for (int k = 0; k < 13; ++k) {
    int i = base + k * 4;
    int4 v = c[k];
    if (i     < n) { cursor[i]     = run; run += v.x; row_ptr[i + 1] = run; }
    if (i + 1 < n) { cursor[i + 1] = run; run += v.y; row_ptr[i + 2] = run; }
    if (i + 2 < n) { cursor[i + 2] = run; run += v.z; row_ptr[i + 3] = run; }
    if (i + 3 < n) { cursor[i + 3] = run; run += v.w; row_ptr[i + 4] = run; }
  }
  if (t == 0) row_ptr[0] = 0;
}

__global__ __launch_bounds__(256) void k_scatter(const int* __restrict__ src,
        const int* __restrict__ dst, int* __restrict__ cursor,
        int* __restrict__ col_src, int E) {
  int e = blockIdx.x * 256 + threadIdx.x;
  if (e >= E) return;
  int slot = atomicAdd(&cursor[dst[e]], 1);
  col_src[slot] = src[e];
}

// ============ one-time converts ============================================

// x (f32) -> xb (bf16), 8 elems/thread
__global__ __launch_bounds__(256) void k_cvt_x(const float* __restrict__ x,
        unsigned short* __restrict__ xb, int total8) {
  int i = blockIdx.x * 256 + threadIdx.x;
  if (i >= total8) return;
  float4 a = ((const float4*)x)[2 * i];
  float4 b = ((const float4*)x)[2 * i + 1];
  uint4 pk;
  pk.x = (unsigned)f2bf(a.x) | ((unsigned)f2bf(a.y) << 16);
  pk.y = (unsigned)f2bf(a.z) | ((unsigned)f2bf(a.w) << 16);
  pk.z = (unsigned)f2bf(b.x) | ((unsigned)f2bf(b.y) << 16);
  pk.w = (unsigned)f2bf(b.z) | ((unsigned)f2bf(b.w) << 16);
  ((uint4*)xb)[i] = pk;
}

// W[l,s][k][col] f32 -> wt[(2l+s)][col][k] bf16 (transposed, K-contiguous)
__global__ void k_cvt_w(const float* __restrict__ Wl, const float* __restrict__ Wr,
        unsigned short* __restrict__ wt) {
  int ls = blockIdx.x;           // 0..5 = layer*2 + side
  int l = ls >> 1, s = ls & 1;
  const float* W = (s ? Wr : Wl) + l * D * D;
  unsigned short* o = wt + ls * D * D;
  for (int it = 0; it < 64; ++it) {
    int idx = it * 256 + threadIdx.x;
    int k = idx >> 7, c = idx & 127;
    o[c * D + k] = f2bf(W[idx]);
  }
}

// ============ GEMM: bf16 MFMA 16x16x32 =====================================
// Block 128 rows x 128 cols (one side), 4 waves, wave = 32 rows x 128 cols.
// x tile in LDS (32KB) with chunk-XOR swizzle (chunk ^= row&7, 16B chunks);
// W read per-fragment from global (L2-resident, broadcast across blocks).
__global__ __launch_bounds__(256) void k_gemm(const unsigned short* __restrict__ xb,
        const unsigned short* __restrict__ wt,   // this layer: [2][128 col][128 k]
        unsigned short* __restrict__ xlb, unsigned short* __restrict__ xrb, int n) {
  __shared__ unsigned short xs[128 * 128];   // 32 KB
  const int t = threadIdx.x;
  const int row0 = blockIdx.x * 128;
  const unsigned short* __restrict__ W = wt + (size_t)blockIdx.y * (D * D);
  unsigned short* __restrict__ outp = blockIdx.y ? xrb : xlb;

  // ---- stage x tile, source pre-permuted so linear LDS + XOR read match ----
#pragma unroll
  for (int i = 0; i < 8; ++i) {
    int ci = i * 256 + t;          // 16B-chunk index 0..2047
    int lr = ci >> 4, p = ci & 15;
    int grow = row0 + lr;
    if (grow >= n) grow = n - 1;   // clamped rows are never stored
    int gp = p ^ (lr & 7);
    uint4 v = *(const uint4*)(xb + (size_t)grow * D + gp * 8);
    *(uint4*)((char*)xs + ci * 16) = v;
  }
  __syncthreads();

  const int lane = t & 63, wv = t >> 6;
  const int colg = lane & 15, kg = lane >> 4;   // frag row/col idx, k-group

  f32x4 acc[2][8];
#pragma unroll
  for (int rr = 0; rr < 2; ++rr)
#pragma unroll
    for (int cc = 0; cc < 8; ++cc) acc[rr][cc] = (f32x4)(0.f);

#pragma unroll
  for (int ks = 0; ks < 4; ++ks) {
    bf16x8 a[2], b[8];
#pragma unroll
    for (int rr = 0; rr < 2; ++rr) {
      int lr = wv * 32 + rr * 16 + colg;
      int byte = (lr * 256 + ks * 64 + kg * 16) ^ ((lr & 7) << 4);
      a[rr] = *(const bf16x8*)((const char*)xs + byte);
    }
#pragma unroll
    for (int cc = 0; cc < 8; ++cc) {
      int col = cc * 16 + colg;
      b[cc] = *(const bf16x8*)(W + (size_t)col * D + ks * 32 + kg * 8);
    }
#pragma unroll
    for (int rr = 0; rr < 2; ++rr)
#pragma unroll
      for (int cc = 0; cc < 8; ++cc)
        acc[rr][cc] = __builtin_amdgcn_mfma_f32_16x16x32_bf16(a[rr], b[cc], acc[rr][cc], 0, 0, 0);
  }

  // ---- epilogue: C/D layout col=lane&15, row=(lane>>4)*4+reg ----
#pragma unroll
  for (int rr = 0; rr < 2; ++rr) {
    int rbase = row0 + wv * 32 + rr * 16 + kg * 4;
#pragma unroll
    for (int cc = 0; cc < 8; ++cc) {
      int col = cc * 16 + colg;
      f32x4 v = acc[rr][cc];
#pragma unroll
      for (int r = 0; r < 4; ++r) {
        int grow = rbase + r;
        if (grow < n) outp[(size_t)grow * D + col] = f2bf(v[r]);
      }
    }
  }
}

// ============ fused score + online-softmax + aggregate =====================
// 16 lanes per node, 4 nodes per wave; xl and xr both bf16.

__global__ __launch_bounds__(256) void k_agg(const unsigned short* __restrict__ xlb,
        const unsigned short* __restrict__ xrb, const int* __restrict__ col_src,
        const int* __restrict__ row_ptr, const float* __restrict__ att,
        float* __restrict__ out, int n) {
  int node = blockIdx.x * 16 + (threadIdx.x >> 4);
  if (node >= n) return;
  int lane = threadIdx.x & 15;
  int ro = lane * 2;                       // float4 index within row
  ushort8_t hr = ((const ushort8_t*)(xrb + (size_t)node * D))[lane];
  float xrv[8];
#pragma unroll
  for (int j = 0; j < 8; ++j) xrv[j] = bf2f(hr[j]);
  float4 at0 = ((const float4*)att)[ro];
  float4 at1 = ((const float4*)att)[ro + 1];
  float atv[8] = {at0.x, at0.y, at0.z, at0.w, at1.x, at1.y, at1.z, at1.w};

  int k0 = row_ptr[node], k1 = row_ptr[node + 1];
  float m = -1e30f, den = 0.f;
  float ac[8];
#pragma unroll
  for (int j = 0; j < 8; ++j) ac[j] = 0.f;

  for (int k = k0; k < k1; ++k) {
    int s = col_src[k];
    ushort8_t hv = ((const ushort8_t*)(xlb + (size_t)s * D))[lane];
    float v[8];
#pragma unroll
    for (int j = 0; j < 8; ++j) v[j] = bf2f(hv[j]);
    float p = 0.f;
#pragma unroll
    for (int j = 0; j < 8; ++j) {
      float tt = v[j] + xrv[j];
      tt = tt > 0.f ? tt : NEG_SLOPE * tt;
      p += tt * atv[j];
    }
    p += __shfl_xor(p, 1);
    p += __shfl_xor(p, 2);
    p += __shfl_xor(p, 4);
    p += __shfl_xor(p, 8);
    if (p > m) {
      float sc = __expf(m - p);
      den *= sc;
#pragma unroll
      for (int j = 0; j < 8; ++j) ac[j] *= sc;
      m = p;
    }
    float a = __expf(p - m);
    den += a;
#pragma unroll
    for (int j = 0; j < 8; ++j) ac[j] += a * v[j];
  }

  float inv = 1.f / (den + 1e-16f);
  float4* o4 = (float4*)out;
  o4[(size_t)node * 32 + ro]     = make_float4(ac[0] * inv, ac[1] * inv, ac[2] * inv, ac[3] * inv);
  o4[(size_t)node * 32 + ro + 1] = make_float4(ac[4] * inv, ac[5] * inv, ac[6] * inv, ac[7] * inv);
}

// ============ BatchNorm + GELU =============================================

__global__ __launch_bounds__(256) void k_bn_stats(const float* __restrict__ agg,
        float* __restrict__ sums, int n) {
  int c = threadIdx.x & 127;
  int half = threadIdx.x >> 7;
  float s = 0.f, s2 = 0.f;
  for (int r = blockIdx.x * 2 + half; r < n; r += gridDim.x * 2) {
    float v = agg[(size_t)r * D + c];
    s += v;
    s2 += v * v;
  }
  atomicAdd(&sums[c], s);
  atomicAdd(&sums[D + c], s2);
}

__global__ void k_bn_fin(const float* __restrict__ sums, const float* __restrict__ gamma,
        const float* __restrict__ beta, float* __restrict__ ss, float inv_n) {
  int c = threadIdx.x;
  float mu = sums[c] * inv_n;
  float var = sums[D + c] * inv_n - mu * mu;
  float rs = rsqrtf(var + BN_EPS);
  float sc = gamma[c] * rs;
  ss[c] = sc;
  ss[D + c] = beta[c] - mu * sc;
}

// writes f32 result AND bf16 mirror (next layer's GEMM input)
__global__ __launch_bounds__(256) void k_bn_apply(const float* __restrict__ agg,
        const float* __restrict__ ss, float* __restrict__ xo,
        unsigned short* __restrict__ xbo, int total4) {
  int i = blockIdx.x * 256 + threadIdx.x;
  if (i >= total4) return;
  float4 v = ((const float4*)agg)[i];
  int c4 = i & (D / 4 - 1);
  float4 sc = ((const float4*)ss)[c4];
  float4 sh = ((const float4*)ss)[D / 4 + c4];
  float y0 = sc.x * v.x + sh.x;
  float y1 = sc.y * v.y + sh.y;
  float y2 = sc.z * v.z + sh.z;
  float y3 = sc.w * v.w + sh.w;
  float4 g;
  g.x = 0.5f * y0 * (1.f + erff(y0 * 0.70710678118654752f));
  g.y = 0.5f * y1 * (1.f + erff(y1 * 0.70710678118654752f));
  g.z = 0.5f * y2 * (1.f + erff(y2 * 0.70710678118654752f));
  g.w = 0.5f * y3 * (1.f + erff(y3 * 0.70710678118654752f));
  ((float4*)xo)[i] = g;
  uint2 pk;
  pk.x = (unsigned)f2bf(g.x) | ((unsigned)f2bf(g.y) << 16);
  pk.y = (unsigned)f2bf(g.z) | ((unsigned)f2bf(g.w) << 16);
  ((uint2*)xbo)[i] = pk;
}

// ===========================================================================

extern "C" void kernel_launch(void* const* d_in, const int* in_sizes, int n_in,
                              void* d_out, int out_size, void* d_ws, size_t ws_size,
                              hipStream_t stream) {
  const float* x0    = (const float*)d_in[0];
  const int*   ei    = (const int*)d_in[1];
  const float* Wl    = (const float*)d_in[2];
  const float* Wr    = (const float*)d_in[3];
  const float* att   = (const float*)d_in[4];
  // d_in[5] = bias: cancelled exactly by BatchNorm mean-subtraction; unused.
  const float* gamma = (const float*)d_in[6];
  const float* beta  = (const float*)d_in[7];
  float* out = (float*)d_out;

  float* ws = (float*)d_ws;
  unsigned short* xb  = (unsigned short*)ws;              // [N][128] bf16 (GEMM input)
  unsigned short* xlb = (unsigned short*)(ws + 3200000);  // [N][128] bf16
  unsigned short* xrb = (unsigned short*)(ws + 6400000);  // [N][128] bf16
  int*   col_src = (int*)(ws + 9600000);        //   800,000
  int*   row_ptr = (int*)(ws + 10400000);       //    50,001
  int*   cursor  = (int*)(ws + 10450004);       //    50,000
  int*   counts  = (int*)(ws + 10500004);       // COUNTS_PAD (16B-aligned)
  float* sums    = ws + 10553252;               //       256
  float* ss      = ws + 10553508;               //       256
  unsigned short* wt = (unsigned short*)(ws + 10553764);  // [3][2][128][128] bf16

  const int* src = ei;
  const int* dst = ei + NEDGES;

  // ---- one-time: CSR build + weight transpose/convert + x convert ----
  hipMemsetAsync(counts, 0, COUNTS_PAD * sizeof(int), stream);
  k_hist<<<(NEDGES + 255) / 256, 256, 0, stream>>>(dst, counts, NEDGES);
  k_scan_all<<<1, SCAN_THREADS, 0, stream>>>(counts, row_ptr, cursor, NNODES);
  k_scatter<<<(NEDGES + 255) / 256, 256, 0, stream>>>(src, dst, cursor, col_src, NEDGES);
  k_cvt_w<<<6, 256, 0, stream>>>(Wl, Wr, wt);
  k_cvt_x<<<(NNODES * (D / 8) + 255) / 256, 256, 0, stream>>>(x0, xb, NNODES * (D / 8));

  dim3 ggrid((NNODES + 127) / 128, 2);

  for (int l = 0; l < 3; ++l) {
    k_gemm<<<ggrid, 256, 0, stream>>>(xb, wt + (size_t)l * 2 * D * D, xlb, xrb, NNODES);
    hipMemsetAsync(sums, 0, 2 * D * sizeof(float), stream);

    // d_out is dead as an input after k_gemm -> safe to overwrite with agg.
    k_agg<<<(NNODES + 15) / 16, 256, 0, stream>>>(xlb, xrb, col_src, row_ptr,
                                                  att + l * D, out, NNODES);

    k_bn_stats<<<512, 256, 0, stream>>>(out, sums, NNODES);
    k_bn_fin<<<1, D, 0, stream>>>(sums, gamma + l * D, beta + l * D, ss, 1.0f / NNODES);
    k_bn_apply<<<(NNODES * (D / 4) + 255) / 256, 256, 0, stream>>>(out, ss, out, xb,
                                                                   NNODES * (D / 4));
  }
}

// Round 11
// 513.501 us; speedup vs baseline: 1.3858x; 1.1424x over previous
//
#include <hip/hip_runtime.h>
#include <math.h>

#define NNODES 50000
#define NEDGES 800000
#define D 128
#define NEG_SLOPE 0.2f
#define BN_EPS 1e-5f
#define SCAN_THREADS 1024
#define WAVE_REGION 3328                      // 52 elems x 64 lanes
#define COUNTS_PAD (16 * WAVE_REGION)         // 53248 >= 50000

typedef __attribute__((ext_vector_type(8))) unsigned short ushort8_t;
typedef __attribute__((ext_vector_type(8))) short bf16x8;
typedef __attribute__((ext_vector_type(4))) float f32x4;

// RNE float -> bf16
__device__ __forceinline__ unsigned short f2bf(float x) {
  unsigned u = __float_as_uint(x);
  u += 0x7fffu + ((u >> 16) & 1u);
  return (unsigned short)(u >> 16);
}
__device__ __forceinline__ float bf2f(unsigned short h) {
  return __uint_as_float((unsigned)h << 16);
}

// ============ CSR build (once per call) ====================================
// rank[e] = position of edge e among edges with the same dst (atomic order)
__global__ __launch_bounds__(256) void k_rank(const int* __restrict__ dst,
        int* __restrict__ counts, int* __restrict__ rank, int E) {
  int e = blockIdx.x * 256 + threadIdx.x;
  if (e < E) rank[e] = atomicAdd(&counts[dst[e]], 1);
}

// Single-WG coalesced scan: wave w owns contiguous region of 3328 counts;
// lane reads counts[rb + j*64 + lane] (coalesced), wave shfl-scan, 16 wave
// totals combined via LDS. Emits row_ptr only.
__global__ __launch_bounds__(1024) void k_scan_all(const int* __restrict__ counts,
        int* __restrict__ row_ptr, int n) {
  __shared__ int wtot[16];
  int t = threadIdx.x;
  int lane = t & 63, w = t >> 6;
  int rb = w * WAVE_REGION;
  // pass 1: wave total (coalesced reads, shfl reduce)
  int tot = 0;
  for (int j = 0; j < 52; ++j) tot += counts[rb + j * 64 + lane];
#pragma unroll
  for (int d = 1; d < 64; d <<= 1) tot += __shfl_xor(tot, d);
  if (lane == 0) wtot[w] = tot;
  __syncthreads();
  int wbase = 0;
#pragma unroll
  for (int i = 0; i < 16; ++i) wbase += (i < w) ? wtot[i] : 0;
  // pass 2: per-group wave scan, emit inclusive prefix (coalesced stores)
  int running = wbase;
  for (int j = 0; j < 52; ++j) {
    int idx = rb + j * 64 + lane;
    int v = counts[idx];
    int incl = v;
#pragma unroll
    for (int d = 1; d < 64; d <<= 1) {
      int u = __shfl_up(incl, d);
      if (lane >= d) incl += u;
    }
    if (idx < n) row_ptr[idx + 1] = running + incl;
    running += __shfl(incl, 63);
  }
  if (t == 0) row_ptr[0] = 0;
}

// atomic-free placement: slot = row_ptr[dst] + rank
__global__ __launch_bounds__(256) void k_place(const int* __restrict__ src,
        const int* __restrict__ dst, const int* __restrict__ rank,
        const int* __restrict__ row_ptr, int* __restrict__ col_src, int E) {
  int e = blockIdx.x * 256 + threadIdx.x;
  if (e >= E) return;
  col_src[row_ptr[dst[e]] + rank[e]] = src[e];
}

// ============ one-time converts ============================================

__global__ __launch_bounds__(256) void k_cvt_x(const float* __restrict__ x,
        unsigned short* __restrict__ xb, int total8) {
  int i = blockIdx.x * 256 + threadIdx.x;
  if (i >= total8) return;
  float4 a = ((const float4*)x)[2 * i];
  float4 b = ((const float4*)x)[2 * i + 1];
  uint4 pk;
  pk.x = (unsigned)f2bf(a.x) | ((unsigned)f2bf(a.y) << 16);
  pk.y = (unsigned)f2bf(a.z) | ((unsigned)f2bf(a.w) << 16);
  pk.z = (unsigned)f2bf(b.x) | ((unsigned)f2bf(b.y) << 16);
  pk.w = (unsigned)f2bf(b.z) | ((unsigned)f2bf(b.w) << 16);
  ((uint4*)xb)[i] = pk;
}

// W[l,s][k][col] f32 -> wt[(2l+s)][col][k] bf16 (transposed, K-contiguous)
__global__ void k_cvt_w(const float* __restrict__ Wl, const float* __restrict__ Wr,
        unsigned short* __restrict__ wt) {
  int ls = blockIdx.x;           // 0..5 = layer*2 + side
  int l = ls >> 1, s = ls & 1;
  const float* W = (s ? Wr : Wl) + l * D * D;
  unsigned short* o = wt + ls * D * D;
  for (int it = 0; it < 64; ++it) {
    int idx = it * 256 + threadIdx.x;
    int k = idx >> 7, c = idx & 127;
    o[c * D + k] = f2bf(W[idx]);
  }
}

// ============ GEMM: bf16 MFMA 16x16x32 =====================================
__global__ __launch_bounds__(256) void k_gemm(const unsigned short* __restrict__ xb,
        const unsigned short* __restrict__ wt,   // this layer: [2][128 col][128 k]
        unsigned short* __restrict__ xlb, unsigned short* __restrict__ xrb, int n) {
  __shared__ unsigned short xs[128 * 128];   // 32 KB
  const int t = threadIdx.x;
  const int row0 = blockIdx.x * 128;
  const unsigned short* __restrict__ W = wt + (size_t)blockIdx.y * (D * D);
  unsigned short* __restrict__ outp = blockIdx.y ? xrb : xlb;

#pragma unroll
  for (int i = 0; i < 8; ++i) {
    int ci = i * 256 + t;          // 16B-chunk index 0..2047
    int lr = ci >> 4, p = ci & 15;
    int grow = row0 + lr;
    if (grow >= n) grow = n - 1;   // clamped rows are never stored
    int gp = p ^ (lr & 7);
    uint4 v = *(const uint4*)(xb + (size_t)grow * D + gp * 8);
    *(uint4*)((char*)xs + ci * 16) = v;
  }
  __syncthreads();

  const int lane = t & 63, wv = t >> 6;
  const int colg = lane & 15, kg = lane >> 4;

  f32x4 acc[2][8];
#pragma unroll
  for (int rr = 0; rr < 2; ++rr)
#pragma unroll
    for (int cc = 0; cc < 8; ++cc) acc[rr][cc] = (f32x4)(0.f);

#pragma unroll
  for (int ks = 0; ks < 4; ++ks) {
    bf16x8 a[2], b[8];
#pragma unroll
    for (int rr = 0; rr < 2; ++rr) {
      int lr = wv * 32 + rr * 16 + colg;
      int byte = (lr * 256 + ks * 64 + kg * 16) ^ ((lr & 7) << 4);
      a[rr] = *(const bf16x8*)((const char*)xs + byte);
    }
#pragma unroll
    for (int cc = 0; cc < 8; ++cc) {
      int col = cc * 16 + colg;
      b[cc] = *(const bf16x8*)(W + (size_t)col * D + ks * 32 + kg * 8);
    }
#pragma unroll
    for (int rr = 0; rr < 2; ++rr)
#pragma unroll
      for (int cc = 0; cc < 8; ++cc)
        acc[rr][cc] = __builtin_amdgcn_mfma_f32_16x16x32_bf16(a[rr], b[cc], acc[rr][cc], 0, 0, 0);
  }

#pragma unroll
  for (int rr = 0; rr < 2; ++rr) {
    int rbase = row0 + wv * 32 + rr * 16 + kg * 4;
#pragma unroll
    for (int cc = 0; cc < 8; ++cc) {
      int col = cc * 16 + colg;
      f32x4 v = acc[rr][cc];
#pragma unroll
      for (int r = 0; r < 4; ++r) {
        int grow = rbase + r;
        if (grow < n) outp[(size_t)grow * D + col] = f2bf(v[r]);
      }
    }
  }
}

// ============ fused score + online-softmax + aggregate =====================

__global__ __launch_bounds__(256) void k_agg(const unsigned short* __restrict__ xlb,
        const unsigned short* __restrict__ xrb, const int* __restrict__ col_src,
        const int* __restrict__ row_ptr, const float* __restrict__ att,
        float* __restrict__ out, int n) {
  int node = blockIdx.x * 16 + (threadIdx.x >> 4);
  if (node >= n) return;
  int lane = threadIdx.x & 15;
  int ro = lane * 2;
  ushort8_t hr = ((const ushort8_t*)(xrb + (size_t)node * D))[lane];
  float xrv[8];
#pragma unroll
  for (int j = 0; j < 8; ++j) xrv[j] = bf2f(hr[j]);
  float4 at0 = ((const float4*)att)[ro];
  float4 at1 = ((const float4*)att)[ro + 1];
  float atv[8] = {at0.x, at0.y, at0.z, at0.w, at1.x, at1.y, at1.z, at1.w};

  int k0 = row_ptr[node], k1 = row_ptr[node + 1];
  float m = -1e30f, den = 0.f;
  float ac[8];
#pragma unroll
  for (int j = 0; j < 8; ++j) ac[j] = 0.f;

  for (int k = k0; k < k1; ++k) {
    int s = col_src[k];
    ushort8_t hv = ((const ushort8_t*)(xlb + (size_t)s * D))[lane];
    float v[8];
#pragma unroll
    for (int j = 0; j < 8; ++j) v[j] = bf2f(hv[j]);
    float p = 0.f;
#pragma unroll
    for (int j = 0; j < 8; ++j) {
      float tt = v[j] + xrv[j];
      tt = tt > 0.f ? tt : NEG_SLOPE * tt;
      p += tt * atv[j];
    }
    p += __shfl_xor(p, 1);
    p += __shfl_xor(p, 2);
    p += __shfl_xor(p, 4);
    p += __shfl_xor(p, 8);
    if (p > m) {
      float sc = __expf(m - p);
      den *= sc;
#pragma unroll
      for (int j = 0; j < 8; ++j) ac[j] *= sc;
      m = p;
    }
    float a = __expf(p - m);
    den += a;
#pragma unroll
    for (int j = 0; j < 8; ++j) ac[j] += a * v[j];
  }

  float inv = 1.f / (den + 1e-16f);
  float4* o4 = (float4*)out;
  o4[(size_t)node * 32 + ro]     = make_float4(ac[0] * inv, ac[1] * inv, ac[2] * inv, ac[3] * inv);
  o4[(size_t)node * 32 + ro + 1] = make_float4(ac[4] * inv, ac[5] * inv, ac[6] * inv, ac[7] * inv);
}

// ============ BatchNorm + GELU =============================================

__global__ __launch_bounds__(256) void k_bn_stats(const float* __restrict__ agg,
        float* __restrict__ sums, int n) {
  int c = threadIdx.x & 127;
  int half = threadIdx.x >> 7;
  float s = 0.f, s2 = 0.f;
  for (int r = blockIdx.x * 2 + half; r < n; r += gridDim.x * 2) {
    float v = agg[(size_t)r * D + c];
    s += v;
    s2 += v * v;
  }
  atomicAdd(&sums[c], s);
  atomicAdd(&sums[D + c], s2);
}

__global__ void k_bn_fin(const float* __restrict__ sums, const float* __restrict__ gamma,
        const float* __restrict__ beta, float* __restrict__ ss, float inv_n) {
  int c = threadIdx.x;
  float mu = sums[c] * inv_n;
  float var = sums[D + c] * inv_n - mu * mu;
  float rs = rsqrtf(var + BN_EPS);
  float sc = gamma[c] * rs;
  ss[c] = sc;
  ss[D + c] = beta[c] - mu * sc;
}

// writes f32 result AND bf16 mirror (next layer's GEMM input)
__global__ __launch_bounds__(256) void k_bn_apply(const float* __restrict__ agg,
        const float* __restrict__ ss, float* __restrict__ xo,
        unsigned short* __restrict__ xbo, int total4) {
  int i = blockIdx.x * 256 + threadIdx.x;
  if (i >= total4) return;
  float4 v = ((const float4*)agg)[i];
  int c4 = i & (D / 4 - 1);
  float4 sc = ((const float4*)ss)[c4];
  float4 sh = ((const float4*)ss)[D / 4 + c4];
  float y0 = sc.x * v.x + sh.x;
  float y1 = sc.y * v.y + sh.y;
  float y2 = sc.z * v.z + sh.z;
  float y3 = sc.w * v.w + sh.w;
  float4 g;
  g.x = 0.5f * y0 * (1.f + erff(y0 * 0.70710678118654752f));
  g.y = 0.5f * y1 * (1.f + erff(y1 * 0.70710678118654752f));
  g.z = 0.5f * y2 * (1.f + erff(y2 * 0.70710678118654752f));
  g.w = 0.5f * y3 * (1.f + erff(y3 * 0.70710678118654752f));
  ((float4*)xo)[i] = g;
  uint2 pk;
  pk.x = (unsigned)f2bf(g.x) | ((unsigned)f2bf(g.y) << 16);
  pk.y = (unsigned)f2bf(g.z) | ((unsigned)f2bf(g.w) << 16);
  ((uint2*)xbo)[i] = pk;
}

// ===========================================================================

extern "C" void kernel_launch(void* const* d_in, const int* in_sizes, int n_in,
                              void* d_out, int out_size, void* d_ws, size_t ws_size,
                              hipStream_t stream) {
  const float* x0    = (const float*)d_in[0];
  const int*   ei    = (const int*)d_in[1];
  const float* Wl    = (const float*)d_in[2];
  const float* Wr    = (const float*)d_in[3];
  const float* att   = (const float*)d_in[4];
  // d_in[5] = bias: cancelled exactly by BatchNorm mean-subtraction; unused.
  const float* gamma = (const float*)d_in[6];
  const float* beta  = (const float*)d_in[7];
  float* out = (float*)d_out;

  float* ws = (float*)d_ws;
  unsigned short* xb  = (unsigned short*)ws;              // [N][128] bf16
  unsigned short* xlb = (unsigned short*)(ws + 3200000);  // [N][128] bf16
  unsigned short* xrb = (unsigned short*)(ws + 6400000);  // [N][128] bf16
  int*   col_src = (int*)(ws + 9600000);        //   800,000
  int*   rank    = (int*)(ws + 10400000);       //   800,000
  int*   row_ptr = (int*)(ws + 11200000);       //    50,001
  int*   counts  = (int*)(ws + 11250004);       // COUNTS_PAD
  float* sums    = ws + 11303252;               //       256
  float* ss      = ws + 11303508;               //       256
  unsigned short* wt = (unsigned short*)(ws + 11303764);  // [3][2][128][128] bf16

  const int* src = ei;
  const int* dst = ei + NEDGES;

  // ---- one-time: CSR build + weight transpose/convert + x convert ----
  hipMemsetAsync(counts, 0, COUNTS_PAD * sizeof(int), stream);
  k_rank<<<(NEDGES + 255) / 256, 256, 0, stream>>>(dst, counts, rank, NEDGES);
  k_scan_all<<<1, SCAN_THREADS, 0, stream>>>(counts, row_ptr, NNODES);
  k_place<<<(NEDGES + 255) / 256, 256, 0, stream>>>(src, dst, rank, row_ptr, col_src, NEDGES);
  k_cvt_w<<<6, 256, 0, stream>>>(Wl, Wr, wt);
  k_cvt_x<<<(NNODES * (D / 8) + 255) / 256, 256, 0, stream>>>(x0, xb, NNODES * (D / 8));

  dim3 ggrid((NNODES + 127) / 128, 2);

  for (int l = 0; l < 3; ++l) {
    k_gemm<<<ggrid, 256, 0, stream>>>(xb, wt + (size_t)l * 2 * D * D, xlb, xrb, NNODES);
    hipMemsetAsync(sums, 0, 2 * D * sizeof(float), stream);

    // d_out is dead as an input after k_gemm -> safe to overwrite with agg.
    k_agg<<<(NNODES + 15) / 16, 256, 0, stream>>>(xlb, xrb, col_src, row_ptr,
                                                  att + l * D, out, NNODES);

    k_bn_stats<<<512, 256, 0, stream>>>(out, sums, NNODES);
    k_bn_fin<<<1, D, 0, stream>>>(sums, gamma + l * D, beta + l * D, ss, 1.0f / NNODES);
    k_bn_apply<<<(NNODES * (D / 4) + 255) / 256, 256, 0, stream>>>(out, ss, out, xb,
                                                                   NNODES * (D / 4));
  }
}